// Round 10
// baseline (214.683 us; speedup 1.0000x reference)
//
#include <hip/hip_runtime.h>
#include <math.h>

typedef unsigned int u32;
typedef unsigned long long u64;
typedef unsigned short ushortT;
typedef __attribute__((ext_vector_type(8))) short short8;
typedef __attribute__((ext_vector_type(4))) float f32x4;

#define Qn    900
#define Bn    16
#define Hn    256
#define NBINS 36
#define NB2   1296
#define T64   64
#define NTILE64 15   // ceil(900/64)
#define NP64  120    // tile pairs ti<=tj
#define NT3   1024   // k3 block size
#define PS    ((size_t)Bn * Qn * Hn)   // bf16 plane stride (elements)
#define TWO_PI_F 6.2831853071795864769f
#define PI_F     3.1415926535897932385f
#define HALF_PI_F 1.5707963267948966f
#define BIN_SIZE_F (TWO_PI_F / 36.0f)
#define BIGV 1e9f

__device__ __forceinline__ u32 fkey(float f) {
    u32 u = __float_as_uint(f);
    return (u & 0x80000000u) ? ~u : (u | 0x80000000u);
}
__device__ __forceinline__ float unfkey(u32 k) {
    u32 u = (k & 0x80000000u) ? (k ^ 0x80000000u) : ~k;
    return __uint_as_float(u);
}
__device__ __forceinline__ float circdist(float a, float b) {
    float diff = fabsf(a - b);
    return fminf(fminf(diff, TWO_PI_F - diff), HALF_PI_F);
}
__device__ __forceinline__ void ins4(float* t4, float v) {
    if (v > t4[3]) {
        if (v > t4[0]) { t4[3]=t4[2]; t4[2]=t4[1]; t4[1]=t4[0]; t4[0]=v; }
        else if (v > t4[1]) { t4[3]=t4[2]; t4[2]=t4[1]; t4[1]=v; }
        else if (v > t4[2]) { t4[3]=t4[2]; t4[2]=v; }
        else t4[3]=v;
    }
}
__device__ __forceinline__ void ins2(float& m1, float& m2, float x) {
    if (x > m1) { m2 = m1; m1 = x; }
    else if (x > m2) m2 = x;
}
// round-to-nearest-even f32 -> bf16, also returns the value it represents
__device__ __forceinline__ ushortT bf16rne(float x, float& back) {
    u32 u = __float_as_uint(x);
    u32 r = u + 0x7FFFu + ((u >> 16) & 1u);
    ushortT h = (ushortT)(r >> 16);
    back = __uint_as_float(((u32)h) << 16);
    return h;
}

// ---------------- K0: angles, bins, counting-sort by bin (1 block / batch) ----
__global__ void k0_sort(const float* __restrict__ pa, float* __restrict__ anglesO,
                        int* __restrict__ binsO, int* __restrict__ sortPos,
                        int* __restrict__ origIdx, int* __restrict__ binSorted,
                        u64* __restrict__ segBest, u32* __restrict__ counter) {
    int b = blockIdx.x, t = threadIdx.x;
    __shared__ int hist[NBINS], offs[NBINS], offs2[NBINS];
    if (t < NBINS) hist[t] = 0;
    if (b == 0 && t == 0) *counter = 0u;
    for (int s = t; s < NB2; s += 256) segBest[(size_t)b * NB2 + s] = 0ULL;
    __syncthreads();
    for (int q = t; q < Qn; q += blockDim.x) {
        float x = pa[(b * Qn + q) * 2 + 0];
        float y = pa[(b * Qn + q) * 2 + 1];
        float a = atan2f(y, x);
        if (a < 0.f) a += TWO_PI_F;
        int bin = (int)(a / BIN_SIZE_F);
        bin = bin < 0 ? 0 : (bin > NBINS - 1 ? NBINS - 1 : bin);
        anglesO[b * Qn + q] = a;
        binsO[b * Qn + q] = bin;
        atomicAdd(&hist[bin], 1);
    }
    __syncthreads();
    if (t == 0) { int s = 0; for (int i = 0; i < NBINS; i++) { offs[i] = s; s += hist[i]; } }
    __syncthreads();
    if (t < NBINS) offs2[t] = offs[t];
    __syncthreads();
    for (int q = t; q < Qn; q += blockDim.x) {
        int bin = binsO[b * Qn + q];
        int pos = atomicAdd(&offs2[bin], 1);
        sortPos[b * Qn + q] = pos;
        origIdx[b * Qn + pos] = q;
        binSorted[b * Qn + pos] = bin;
    }
}

// ---------------- K1: fused+normalize, split into 3 bf16 planes (sorted) -----
__global__ void k1_norm(const float4* __restrict__ qf, const float4* __restrict__ W,
                        const int* __restrict__ binsO, const int* __restrict__ sortPos,
                        ushortT* __restrict__ nqB) {
    int b = blockIdx.x;
    int w = threadIdx.x >> 6, lane = threadIdx.x & 63;
    int q = blockIdx.y * 4 + w;  // grid.y = 225, 900 = 4*225
    int bin = binsO[b * Qn + q];
    float4 v = qf[(size_t)(b * Qn + q) * (Hn / 4) + lane];
    float4 wv = W[(size_t)bin * (Hn / 4) + lane];
    v.x += wv.x; v.y += wv.y; v.z += wv.z; v.w += wv.w;
    float ss = v.x * v.x + v.y * v.y + v.z * v.z + v.w * v.w;
    #pragma unroll
    for (int off = 32; off >= 1; off >>= 1) ss += __shfl_xor(ss, off, 64);
    float sc = 1.f / fmaxf(sqrtf(ss), 1e-12f);
    float xs[4] = {v.x * sc, v.y * sc, v.z * sc, v.w * sc};
    ushort4 p0, p1, p2;
    ushortT* h0 = (ushortT*)&p0; ushortT* h1 = (ushortT*)&p1; ushortT* h2 = (ushortT*)&p2;
    #pragma unroll
    for (int c = 0; c < 4; c++) {
        float f0, f1, f2;
        h0[c] = bf16rne(xs[c], f0);
        float r1 = xs[c] - f0;
        h1[c] = bf16rne(r1, f1);
        float r2 = r1 - f1;
        h2[c] = bf16rne(r2, f2);
    }
    int sp = sortPos[b * Qn + q];
    size_t base = ((size_t)(b * Qn + sp)) * Hn + lane * 4;
    *(ushort4*)(nqB + 0 * PS + base) = p0;
    *(ushort4*)(nqB + 1 * PS + base) = p1;
    *(ushort4*)(nqB + 2 * PS + base) = p2;
}

// ---------------- K2: MFMA pair-sim GEMM + segment argmax + top4 -------------
// R9 lesson: LDS port was the wall (~35us of reads+DMA-writes+atomics between
// 16 barrier drains/block). -> load MFMA fragments DIRECTLY from global (L2):
// lane lm reads 16B at row base+lm, k-offset lq*8; the 4 lq lanes per row form
// one contiguous 64B line -> clean coalescing. K-loop has ZERO LDS traffic and
// ZERO barriers (waves independent; compiler pipelines with fine vmcnt).
// LDS keeps only segLds+metadata (11.5KB). Same values, same MFMA order ->
// bit-identical results. Emission stays in the proven LDS-aggregation shape
// (R2/R5/R7 spill lessons).
__global__ __launch_bounds__(256, 4) void k2_gemm(
        const ushortT* __restrict__ nqB, const int* __restrict__ binSorted,
        const int* __restrict__ origIdx, u64* __restrict__ segBest,
        float* __restrict__ topCand) {
    __shared__ u64 segLds[NB2];
    __shared__ int rbins[T64], cbins[T64], rois[T64], cois[T64];
    __shared__ float t4w[16];

    int lin = blockIdx.x;
    int xcd = lin & 7;
    int slot = lin >> 3;                 // 0..239
    int b = xcd * 2 + (slot >= NP64 ? 1 : 0);
    int tp = (slot >= NP64) ? slot - NP64 : slot;
    int ti = 0, rem = tp;
    while (rem >= NTILE64 - ti) { rem -= NTILE64 - ti; ti++; }
    int tj = ti + rem;
    int rowBase = ti * T64, colBase = tj * T64;
    int t = threadIdx.x;
    int w = t >> 6, lane = t & 63;
    int wrow = w >> 1, wcol = w & 1;
    int lq = lane >> 4, lm = lane & 15;

    for (int s = t; s < NB2; s += 256) segLds[s] = 0ULL;
    if (t < T64) {
        int sr = rowBase + t, sc = colBase + t;
        rbins[t] = (sr < Qn) ? binSorted[b * Qn + sr] : 0;
        rois[t]  = (sr < Qn) ? origIdx[b * Qn + sr] : 0;
        cbins[t] = (sc < Qn) ? binSorted[b * Qn + sc] : 0;
        cois[t]  = (sc < Qn) ? origIdx[b * Qn + sc] : 0;
    }
    // NOTE: no barrier here — the one after the K-loop orders this vs emission.

    f32x4 acc[2][2];
    #pragma unroll
    for (int i = 0; i < 2; i++)
        #pragma unroll
        for (int j = 0; j < 2; j++) acc[i][j] = (f32x4){0.f, 0.f, 0.f, 0.f};

    // per-lane fragment row pointers (A rows for mt=0/1, B rows for nt=0/1)
    int rA0 = rowBase + wrow * 32 + lm;       if (rA0 >= Qn) rA0 = Qn - 1;
    int rA1 = rowBase + wrow * 32 + 16 + lm;  if (rA1 >= Qn) rA1 = Qn - 1;
    int rB0 = colBase + wcol * 32 + lm;       if (rB0 >= Qn) rB0 = Qn - 1;
    int rB1 = colBase + wcol * 32 + 16 + lm;  if (rB1 >= Qn) rB1 = Qn - 1;
    const ushortT* pA0 = nqB + (size_t)(b * Qn + rA0) * Hn + lq * 8;
    const ushortT* pA1 = nqB + (size_t)(b * Qn + rA1) * Hn + lq * 8;
    const ushortT* pB0 = nqB + (size_t)(b * Qn + rB0) * Hn + lq * 8;
    const ushortT* pB1 = nqB + (size_t)(b * Qn + rB1) * Hn + lq * 8;

    #pragma unroll 2
    for (int kc = 0; kc < Hn; kc += 32) {
        short8 a00 = *(const short8*)(pA0 + kc);
        short8 a01 = *(const short8*)(pA0 + PS + kc);
        short8 a02 = *(const short8*)(pA0 + 2 * PS + kc);
        short8 a10 = *(const short8*)(pA1 + kc);
        short8 a11 = *(const short8*)(pA1 + PS + kc);
        short8 a12 = *(const short8*)(pA1 + 2 * PS + kc);
        short8 b00 = *(const short8*)(pB0 + kc);
        short8 b01 = *(const short8*)(pB0 + PS + kc);
        short8 b02 = *(const short8*)(pB0 + 2 * PS + kc);
        short8 b10 = *(const short8*)(pB1 + kc);
        short8 b11 = *(const short8*)(pB1 + PS + kc);
        short8 b12 = *(const short8*)(pB1 + 2 * PS + kc);

        // same per-accumulator MFMA sequence as previous rounds (bit-exact):
        // nt outer, mt inner; chain a0b0,a0b1,a1b0,a1b1,a0b2,a2b0
        {   // nt = 0
            f32x4 c = acc[0][0];
            c = __builtin_amdgcn_mfma_f32_16x16x32_bf16(a00, b00, c, 0, 0, 0);
            c = __builtin_amdgcn_mfma_f32_16x16x32_bf16(a00, b01, c, 0, 0, 0);
            c = __builtin_amdgcn_mfma_f32_16x16x32_bf16(a01, b00, c, 0, 0, 0);
            c = __builtin_amdgcn_mfma_f32_16x16x32_bf16(a01, b01, c, 0, 0, 0);
            c = __builtin_amdgcn_mfma_f32_16x16x32_bf16(a00, b02, c, 0, 0, 0);
            c = __builtin_amdgcn_mfma_f32_16x16x32_bf16(a02, b00, c, 0, 0, 0);
            acc[0][0] = c;
            c = acc[1][0];
            c = __builtin_amdgcn_mfma_f32_16x16x32_bf16(a10, b00, c, 0, 0, 0);
            c = __builtin_amdgcn_mfma_f32_16x16x32_bf16(a10, b01, c, 0, 0, 0);
            c = __builtin_amdgcn_mfma_f32_16x16x32_bf16(a11, b00, c, 0, 0, 0);
            c = __builtin_amdgcn_mfma_f32_16x16x32_bf16(a11, b01, c, 0, 0, 0);
            c = __builtin_amdgcn_mfma_f32_16x16x32_bf16(a10, b02, c, 0, 0, 0);
            c = __builtin_amdgcn_mfma_f32_16x16x32_bf16(a12, b00, c, 0, 0, 0);
            acc[1][0] = c;
        }
        {   // nt = 1
            f32x4 c = acc[0][1];
            c = __builtin_amdgcn_mfma_f32_16x16x32_bf16(a00, b10, c, 0, 0, 0);
            c = __builtin_amdgcn_mfma_f32_16x16x32_bf16(a00, b11, c, 0, 0, 0);
            c = __builtin_amdgcn_mfma_f32_16x16x32_bf16(a01, b10, c, 0, 0, 0);
            c = __builtin_amdgcn_mfma_f32_16x16x32_bf16(a01, b11, c, 0, 0, 0);
            c = __builtin_amdgcn_mfma_f32_16x16x32_bf16(a00, b12, c, 0, 0, 0);
            c = __builtin_amdgcn_mfma_f32_16x16x32_bf16(a02, b10, c, 0, 0, 0);
            acc[0][1] = c;
            c = acc[1][1];
            c = __builtin_amdgcn_mfma_f32_16x16x32_bf16(a10, b10, c, 0, 0, 0);
            c = __builtin_amdgcn_mfma_f32_16x16x32_bf16(a10, b11, c, 0, 0, 0);
            c = __builtin_amdgcn_mfma_f32_16x16x32_bf16(a11, b10, c, 0, 0, 0);
            c = __builtin_amdgcn_mfma_f32_16x16x32_bf16(a11, b11, c, 0, 0, 0);
            c = __builtin_amdgcn_mfma_f32_16x16x32_bf16(a10, b12, c, 0, 0, 0);
            c = __builtin_amdgcn_mfma_f32_16x16x32_bf16(a12, b10, c, 0, 0, 0);
            acc[1][1] = c;
        }
    }

    __syncthreads();   // segLds zero + rbins loads complete before emission

    // ---- emission: C/D layout col=lm, row=lq*4+reg (m89-verified) ----
    float t4[4] = {-3e38f, -3e38f, -3e38f, -3e38f};
    int curSeg = -1; u64 curBest = 0ULL;
    #pragma unroll
    for (int mt = 0; mt < 2; mt++) {
        #pragma unroll
        for (int r = 0; r < 4; r++) {
            int lrr = wrow * 32 + mt * 16 + lq * 4 + r;
            int sr = rowBase + lrr;
            int bi = rbins[lrr], io = rois[lrr];
            #pragma unroll
            for (int nt = 0; nt < 2; nt++) {
                int lcc = wcol * 32 + nt * 16 + lm;
                int sc = colBase + lcc;
                bool ok = (sr < Qn) && (sc < Qn) && (sr < sc);
                if (ok) {
                    float v = acc[mt][nt][r];
                    ins4(t4, v);
                    int bj = cbins[lcc], jo = cois[lcc];
                    int bmin = bi < bj ? bi : bj, bmax = bi < bj ? bj : bi;
                    int seg = bmin * NBINS + bmax;
                    int imin = io < jo ? io : jo, jmax = io < jo ? jo : io;
                    u64 packed = ((u64)fkey(v) << 32) | (u32)(~(((u32)imin << 10) | (u32)jmax));
                    if (seg == curSeg) { if (packed > curBest) curBest = packed; }
                    else {
                        if (curSeg >= 0) atomicMax(&segLds[curSeg], curBest);
                        curSeg = seg; curBest = packed;
                    }
                }
            }
        }
    }
    if (curSeg >= 0) atomicMax(&segLds[curSeg], curBest);

    // wave-level top4 shuffle merge
    #pragma unroll
    for (int off = 32; off >= 1; off >>= 1) {
        float o0 = __shfl_xor(t4[0], off, 64);
        float o1 = __shfl_xor(t4[1], off, 64);
        float o2 = __shfl_xor(t4[2], off, 64);
        float o3 = __shfl_xor(t4[3], off, 64);
        ins4(t4, o0); ins4(t4, o1); ins4(t4, o2); ins4(t4, o3);
    }
    if (lane == 0) {
        t4w[w * 4 + 0] = t4[0]; t4w[w * 4 + 1] = t4[1];
        t4w[w * 4 + 2] = t4[2]; t4w[w * 4 + 3] = t4[3];
    }
    __syncthreads();

    for (int s = t; s < NB2; s += 256) {
        u64 v = segLds[s];
        if (v) atomicMax(&segBest[(size_t)b * NB2 + s], v);
    }
    if (t == 0) {
        #pragma unroll
        for (int ww = 1; ww < 4; ww++) {
            ins4(t4, t4w[ww * 4 + 0]); ins4(t4, t4w[ww * 4 + 1]);
            ins4(t4, t4w[ww * 4 + 2]); ins4(t4, t4w[ww * 4 + 3]);
        }
        float* dst = topCand + (size_t)(b * NP64 + tp) * 4;
        dst[0] = t4[0]; dst[1] = t4[1]; dst[2] = t4[2]; dst[3] = t4[3];
    }
}

// ---------------- K3 helpers (NT3 = 1024) ------------------------------------
__device__ __forceinline__ int blockSumI(int v, volatile int* red) {
    #pragma unroll
    for (int off = 32; off >= 1; off >>= 1) v += __shfl_xor(v, off, 64);
    int w = threadIdx.x >> 6;
    if ((threadIdx.x & 63) == 0) red[w] = v;
    __syncthreads();
    if (threadIdx.x < 64) {
        int x = (threadIdx.x < 16) ? red[threadIdx.x] : 0;
        #pragma unroll
        for (int off = 8; off >= 1; off >>= 1) x += __shfl_xor(x, off, 64);
        if (threadIdx.x == 0) red[0] = x;
    }
    __syncthreads();
    int r = red[0];
    __syncthreads();
    return r;
}
__device__ __forceinline__ float blockSumF(float v, volatile float* red) {
    #pragma unroll
    for (int off = 32; off >= 1; off >>= 1) v += __shfl_xor(v, off, 64);
    int w = threadIdx.x >> 6;
    if ((threadIdx.x & 63) == 0) red[w] = v;
    __syncthreads();
    if (threadIdx.x < 64) {
        float x = (threadIdx.x < 16) ? red[threadIdx.x] : 0.f;
        #pragma unroll
        for (int off = 8; off >= 1; off >>= 1) x += __shfl_xor(x, off, 64);
        if (threadIdx.x == 0) red[0] = x;
    }
    __syncthreads();
    float r = red[0];
    __syncthreads();
    return r;
}
__device__ __forceinline__ u32 blockMinU(u32 v, volatile u32* red) {
    #pragma unroll
    for (int off = 32; off >= 1; off >>= 1) {
        u32 o = (u32)__shfl_xor((int)v, off, 64);
        v = v < o ? v : o;
    }
    int w = threadIdx.x >> 6;
    if ((threadIdx.x & 63) == 0) red[w] = v;
    __syncthreads();
    if (threadIdx.x < 64) {
        u32 x = (threadIdx.x < 16) ? red[threadIdx.x] : 0xFFFFFFFFu;
        #pragma unroll
        for (int off = 8; off >= 1; off >>= 1) {
            u32 o = (u32)__shfl_xor((int)x, off, 64);
            x = x < o ? x : o;
        }
        if (threadIdx.x == 0) red[0] = x;
    }
    __syncthreads();
    u32 r = red[0];
    __syncthreads();
    return r;
}
// block top-2 (max, 2nd max incl. duplicates); inputs per-thread (m1,m2)
__device__ void blockTop2(float m1, float m2, volatile float* red2, float& o1, float& o2) {
    #pragma unroll
    for (int off = 32; off >= 1; off >>= 1) {
        float a1 = __shfl_xor(m1, off, 64);
        float a2 = __shfl_xor(m2, off, 64);
        ins2(m1, m2, a1); ins2(m1, m2, a2);
    }
    int w = threadIdx.x >> 6;
    if ((threadIdx.x & 63) == 0) { red2[w * 2] = m1; red2[w * 2 + 1] = m2; }
    __syncthreads();
    if (threadIdx.x == 0) {
        float r1 = red2[0], r2 = red2[1];
        for (int ww = 1; ww < 16; ww++) { ins2(r1, r2, red2[ww * 2]); ins2(r1, r2, red2[ww * 2 + 1]); }
        red2[0] = r1; red2[1] = r2;
    }
    __syncthreads();
    o1 = red2[0]; o2 = red2[1];
    __syncthreads();
}

// Count-based rank selection (used only for the tiny median set).
__device__ void selectTwoC(const u32* ckeys, int m, int mp, int p0, int p1,
                           u32& r0, u32& r1, volatile u32* redU) {
    int t = threadIdx.x;
    u32 kA = (t < m) ? ckeys[t] : 0xFFFFFFFFu;
    u32 kB = (t + NT3 < m) ? ckeys[t + NT3] : 0xFFFFFFFFu;
    int cA = 0, cB = 0;
    if (t < m) {
        const uint4* c4 = (const uint4*)ckeys;
        for (int g = 0; g < mp / 16; g++) {
            uint4 a = c4[g * 4 + 0], bq = c4[g * 4 + 1];
            uint4 c = c4[g * 4 + 2], d = c4[g * 4 + 3];
            u32 ys[16] = {a.x, a.y, a.z, a.w, bq.x, bq.y, bq.z, bq.w,
                          c.x, c.y, c.z, c.w, d.x, d.y, d.z, d.w};
            #pragma unroll
            for (int j = 0; j < 16; j++) {
                cA += (ys[j] <= kA);
                cB += (ys[j] <= kB);
            }
        }
    }
    u32 q0 = 0xFFFFFFFFu, q1 = 0xFFFFFFFFu;
    if (cA >= p0 + 1 && kA < q0) q0 = kA;
    if (cB >= p0 + 1 && kB < q0) q0 = kB;
    if (cA >= p1 + 1 && kA < q1) q1 = kA;
    if (cB >= p1 + 1 && kB < q1) q1 = kB;
    r0 = blockMinU(q0, redU);
    r1 = blockMinU(q1, redU);
}

// masked quantile at q=1-1/(n+1): pos = n-2 + 2/(n+1) -> lo=n-2, hi=n-1,
// i.e. interpolation between 2nd-max and max (same float arithmetic as ref).
__device__ __forceinline__ float quantTop2(float top1, float top2, int n) {
    float nf = (float)n;
    float qq = 1.f - 1.f / (nf + 1.f);
    float pos = qq * fmaxf(nf - 1.f, 0.f);
    int lo = (int)floorf(pos), hi = (int)ceilf(pos);
    float frac = pos - (float)lo;
    float slo = (lo >= n - 1) ? top1 : top2;
    float shi = (hi >= n - 1) ? top1 : top2;
    return slo + (shi - slo) * frac;
}

// ---------------- K3: per-batch scalar tail + fused final combine ------------
__global__ __launch_bounds__(1024) void k3_final(
        const u64* __restrict__ segBest, const float* __restrict__ anglesO,
        const float* __restrict__ topCand, float* __restrict__ batchRes,
        u32* __restrict__ counter, float* __restrict__ out) {
    int b = blockIdx.x, t = threadIdx.x;
    int lane = t & 63;
    __shared__ float sval[NB2], sd[NB2], sai[NB2], saj[NB2];
    __shared__ unsigned char svalid[NB2], smF[NB2];
    __shared__ __align__(16) u32 ckeys[NB2 + 16];
    __shared__ int redI[32];
    __shared__ float redF[32];
    __shared__ u32 redU[32];
    __shared__ float red2[32];
    __shared__ int mcnt;
    __shared__ float sth2;

    for (int s = t; s < NB2; s += NT3) {
        u64 p = segBest[(size_t)b * NB2 + s];
        bool v = (p != 0ULL);
        float val = 0.f, ai = 0.f, aj = 0.f, d = 0.f;
        if (v) {
            val = unfkey((u32)(p >> 32));
            u32 code = ~((u32)p);
            int i = (code >> 10) & 1023, j = code & 1023;
            ai = anglesO[b * Qn + i]; aj = anglesO[b * Qn + j];
            d = circdist(ai, aj);
        }
        sval[s] = val; sai[s] = ai; saj[s] = aj; sd[s] = d;
        svalid[s] = v ? 1 : 0;
    }
    __syncthreads();

    // ---- S + top2 of valid sims -> thr ----
    int Sv = 0;
    float m1 = -3e38f, m2 = -3e38f;
    for (int s = t; s < NB2; s += NT3) {
        if (svalid[s]) { Sv++; ins2(m1, m2, sval[s]); }
    }
    int S = blockSumI(Sv, redI);
    float top1, top2v;
    blockTop2(m1, m2, red2, top1, top2v);
    float thr = (S == 0) ? BIGV : quantTop2(top1, top2v, S);

    int c1v = 0;
    for (int s = t; s < NB2; s += NT3) if (svalid[s] && sval[s] > thr) c1v++;
    int c1 = blockSumI(c1v, redI);

    // ---- th2 = 4th-largest pair sim (wave-0 top4 shuffle merge) ----
    if (t < 64) {
        float t4[4] = {-3e38f, -3e38f, -3e38f, -3e38f};
        for (int i = t; i < NP64 * 4; i += 64) ins4(t4, topCand[(size_t)b * NP64 * 4 + i]);
        #pragma unroll
        for (int off = 32; off >= 1; off >>= 1) {
            float o0 = __shfl_xor(t4[0], off, 64);
            float o1 = __shfl_xor(t4[1], off, 64);
            float o2 = __shfl_xor(t4[2], off, 64);
            float o3 = __shfl_xor(t4[3], off, 64);
            ins4(t4, o0); ins4(t4, o1); ins4(t4, o2); ins4(t4, o3);
        }
        if (t == 0) sth2 = t4[3];
    }
    __syncthreads();
    float th2 = sth2;

    bool use_fb = (c1 < 2);
    int cv = 0;
    for (int s = t; s < NB2; s += NT3) {
        bool mF = use_fb ? (svalid[s] && sval[s] >= th2) : (svalid[s] && sval[s] > thr);
        smF[s] = mF ? 1 : 0;
        cv += mF ? 1 : 0;
    }
    int cnt = blockSumI(cv, redI);

    // ---- median of masked d: compact (tiny set) + rank select ----
    if (t == 0) mcnt = 0;
    __syncthreads();
    for (int s = t; s < NB2; s += NT3) {
        bool pred = smF[s] != 0;
        u32 key = fkey(sd[s]);
        u64 bal = __ballot(pred);
        int prefix = __popcll(bal & ((1ULL << lane) - 1ULL));
        int tot = __popcll(bal);
        int base = 0;
        if (lane == 0) base = tot ? atomicAdd(&mcnt, tot) : 0;
        base = __shfl(base, 0, 64);
        if (pred) ckeys[base + prefix] = key;
    }
    __syncthreads();
    int m2c = mcnt;
    int mp2 = (m2c + 15) & ~15;
    for (int s = m2c + t; s < mp2; s += NT3) ckeys[s] = 0xFFFFFFFFu;
    __syncthreads();

    float med;
    if (cnt == 0) med = BIGV;
    else {
        int midx = (cnt - 1) >> 1;
        u32 kk0, kk1;
        selectTwoC(ckeys, m2c, mp2, midx, midx, kk0, kk1, redU);
        med = unfkey(kk0);
    }
    float alpha = fminf(fmaxf(med, PI_F / (float)NBINS), HALF_PI_F);

    // ---- coop stats + comp count/top2 in one pass ----
    int ncoopv = 0, ncompv = 0; float coopv = 0.f;
    float c1m = -3e38f, c2m = -3e38f;
    for (int s = t; s < NB2; s += NT3) {
        if (!smF[s]) continue;
        if (sd[s] <= alpha) {
            ncoopv++;
            float ai = sai[s], aj = saj[s];
            float mm = atan2f((sinf(ai) + sinf(aj)) * 0.5f, (cosf(ai) + cosf(aj)) * 0.5f);
            float d1 = circdist(ai, mm), d2 = circdist(aj, mm);
            coopv += d1 * d1 + d2 * d2;
        } else {
            ncompv++;
            ins2(c1m, c2m, sval[s]);
        }
    }
    int ncoop = blockSumI(ncoopv, redI);
    float coopSum = blockSumF(coopv, redF);
    int ncomp = blockSumI(ncompv, redI);
    float ct1, ct2;
    blockTop2(c1m, c2m, red2, ct1, ct2);
    float margin = (ncomp == 0) ? BIGV : quantTop2(ct1, ct2, ncomp);

    float compv = 0.f;
    for (int s = t; s < NB2; s += NT3) {
        if (smF[s] && sd[s] > alpha) {
            float viol = fmaxf(sval[s] - margin, 0.f);
            compv += viol * viol;
        }
    }
    float compSum = blockSumF(compv, redF);

    // fused final combine: last-finished block reduces all batchRes.
    if (t == 0) {
        float r0 = coopSum / (float)(ncoop > 1 ? ncoop : 1);
        float r1 = compSum / (float)(ncomp > 1 ? ncomp : 1);
        float r2 = cnt > 0 ? 1.f : 0.f;
        __hip_atomic_store(&batchRes[b * 3 + 0], r0, __ATOMIC_RELEASE, __HIP_MEMORY_SCOPE_AGENT);
        __hip_atomic_store(&batchRes[b * 3 + 1], r1, __ATOMIC_RELEASE, __HIP_MEMORY_SCOPE_AGENT);
        __hip_atomic_store(&batchRes[b * 3 + 2], r2, __ATOMIC_RELEASE, __HIP_MEMORY_SCOPE_AGENT);
        u32 done = __hip_atomic_fetch_add(counter, 1u, __ATOMIC_ACQ_REL, __HIP_MEMORY_SCOPE_AGENT);
        if (done == Bn - 1) {
            float cs = 0.f, ps = 0.f, vs = 0.f;
            for (int bb = 0; bb < Bn; bb++) {
                cs += __hip_atomic_load(&batchRes[bb * 3 + 0], __ATOMIC_ACQUIRE, __HIP_MEMORY_SCOPE_AGENT);
                ps += __hip_atomic_load(&batchRes[bb * 3 + 1], __ATOMIC_ACQUIRE, __HIP_MEMORY_SCOPE_AGENT);
                vs += __hip_atomic_load(&batchRes[bb * 3 + 2], __ATOMIC_ACQUIRE, __HIP_MEMORY_SCOPE_AGENT);
            }
            float denom = fmaxf(vs, 1.f);
            out[0] = cs / denom;
            out[1] = ps / denom;
        }
    }
}

extern "C" void kernel_launch(void* const* d_in, const int* in_sizes, int n_in,
                              void* d_out, int out_size, void* d_ws, size_t ws_size,
                              hipStream_t stream) {
    (void)in_sizes; (void)n_in; (void)out_size; (void)ws_size;
    const float* qf = (const float*)d_in[0];
    const float* pa = (const float*)d_in[1];
    const float* W  = (const float*)d_in[2];
    float* out = (float*)d_out;

    char* ws = (char*)d_ws;
    size_t off = 0;
    ushortT* nqB = (ushortT*)(ws + off);  off += 3 * PS * 2;                 // 22.1 MB
    float* anglesO = (float*)(ws + off);  off += (size_t)Bn * Qn * 4;
    int* binsO = (int*)(ws + off);        off += (size_t)Bn * Qn * 4;
    int* sortPos = (int*)(ws + off);      off += (size_t)Bn * Qn * 4;
    int* origIdx = (int*)(ws + off);      off += (size_t)Bn * Qn * 4;
    int* binSorted = (int*)(ws + off);    off += (size_t)Bn * Qn * 4;
    u64* segBest = (u64*)(ws + off);      off += (size_t)Bn * NB2 * 8;
    float* topCand = (float*)(ws + off);  off += (size_t)Bn * NP64 * 4 * 4;
    float* batchRes = (float*)(ws + off); off += (size_t)Bn * 3 * 4;
    u32* counter = (u32*)(ws + off);      off += 64;

    k0_sort<<<Bn, 256, 0, stream>>>(pa, anglesO, binsO, sortPos, origIdx, binSorted,
                                    segBest, counter);
    k1_norm<<<dim3(Bn, 225), 256, 0, stream>>>((const float4*)qf, (const float4*)W,
                                               binsO, sortPos, nqB);
    k2_gemm<<<NP64 * Bn, 256, 0, stream>>>(nqB, binSorted, origIdx, segBest, topCand);
    k3_final<<<Bn, 1024, 0, stream>>>(segBest, anglesO, topCand, batchRes, counter, out);
}

// Round 11
// 158.617 us; speedup vs baseline: 1.3535x; 1.3535x over previous
//
#include <hip/hip_runtime.h>
#include <math.h>

typedef unsigned int u32;
typedef unsigned long long u64;
typedef unsigned short ushortT;
typedef __attribute__((ext_vector_type(8))) short short8;
typedef __attribute__((ext_vector_type(4))) float f32x4;

#define Qn    900
#define Bn    16
#define Hn    256
#define NBINS 36
#define NB2   1296
#define T64   64
#define NTILE64 15   // ceil(900/64)
#define NP64  120    // tile pairs ti<=tj
#define NT3   1024   // k3 block size
#define PS    ((size_t)Bn * Qn * Hn)   // bf16 plane stride (elements)
#define TWO_PI_F 6.2831853071795864769f
#define PI_F     3.1415926535897932385f
#define HALF_PI_F 1.5707963267948966f
#define BIN_SIZE_F (TWO_PI_F / 36.0f)
#define BIGV 1e9f

__device__ __forceinline__ u32 fkey(float f) {
    u32 u = __float_as_uint(f);
    return (u & 0x80000000u) ? ~u : (u | 0x80000000u);
}
__device__ __forceinline__ float unfkey(u32 k) {
    u32 u = (k & 0x80000000u) ? (k ^ 0x80000000u) : ~k;
    return __uint_as_float(u);
}
__device__ __forceinline__ float circdist(float a, float b) {
    float diff = fabsf(a - b);
    return fminf(fminf(diff, TWO_PI_F - diff), HALF_PI_F);
}
__device__ __forceinline__ void ins4(float* t4, float v) {
    if (v > t4[3]) {
        if (v > t4[0]) { t4[3]=t4[2]; t4[2]=t4[1]; t4[1]=t4[0]; t4[0]=v; }
        else if (v > t4[1]) { t4[3]=t4[2]; t4[2]=t4[1]; t4[1]=v; }
        else if (v > t4[2]) { t4[3]=t4[2]; t4[2]=v; }
        else t4[3]=v;
    }
}
__device__ __forceinline__ void ins2(float& m1, float& m2, float x) {
    if (x > m1) { m2 = m1; m1 = x; }
    else if (x > m2) m2 = x;
}
// round-to-nearest-even f32 -> bf16, also returns the value it represents
__device__ __forceinline__ ushortT bf16rne(float x, float& back) {
    u32 u = __float_as_uint(x);
    u32 r = u + 0x7FFFu + ((u >> 16) & 1u);
    ushortT h = (ushortT)(r >> 16);
    back = __uint_as_float(((u32)h) << 16);
    return h;
}
// async global->LDS, 16B per lane. HW semantics: wave-uniform base + lane*16.
__device__ __forceinline__ void gl_lds16(const ushortT* g, ushortT* l) {
    __builtin_amdgcn_global_load_lds(
        (const __attribute__((address_space(1))) unsigned int*)g,
        (__attribute__((address_space(3))) unsigned int*)l,
        16, 0, 0);
}

// ---------------- K0: angles, bins, counting-sort by bin (1 block / batch) ----
__global__ void k0_sort(const float* __restrict__ pa, float* __restrict__ anglesO,
                        int* __restrict__ binsO, int* __restrict__ sortPos,
                        int* __restrict__ origIdx, int* __restrict__ binSorted,
                        u64* __restrict__ segBest, u32* __restrict__ counter) {
    int b = blockIdx.x, t = threadIdx.x;
    __shared__ int hist[NBINS], offs[NBINS], offs2[NBINS];
    if (t < NBINS) hist[t] = 0;
    if (b == 0 && t == 0) *counter = 0u;
    for (int s = t; s < NB2; s += 256) segBest[(size_t)b * NB2 + s] = 0ULL;
    __syncthreads();
    for (int q = t; q < Qn; q += blockDim.x) {
        float x = pa[(b * Qn + q) * 2 + 0];
        float y = pa[(b * Qn + q) * 2 + 1];
        float a = atan2f(y, x);
        if (a < 0.f) a += TWO_PI_F;
        int bin = (int)(a / BIN_SIZE_F);
        bin = bin < 0 ? 0 : (bin > NBINS - 1 ? NBINS - 1 : bin);
        anglesO[b * Qn + q] = a;
        binsO[b * Qn + q] = bin;
        atomicAdd(&hist[bin], 1);
    }
    __syncthreads();
    if (t == 0) { int s = 0; for (int i = 0; i < NBINS; i++) { offs[i] = s; s += hist[i]; } }
    __syncthreads();
    if (t < NBINS) offs2[t] = offs[t];
    __syncthreads();
    for (int q = t; q < Qn; q += blockDim.x) {
        int bin = binsO[b * Qn + q];
        int pos = atomicAdd(&offs2[bin], 1);
        sortPos[b * Qn + q] = pos;
        origIdx[b * Qn + pos] = q;
        binSorted[b * Qn + pos] = bin;
    }
}

// ---------------- K1: fused+normalize, split into 2 bf16 planes (sorted) -----
// bf16x2: x = b0 + b1 (RNE extractions), rep error ~2^-17. k2's 4-MFMA
// combination is exact within this representation -> sim error ~1.5e-5,
// far below the 1.55e-2 absmax threshold.
__global__ void k1_norm(const float4* __restrict__ qf, const float4* __restrict__ W,
                        const int* __restrict__ binsO, const int* __restrict__ sortPos,
                        ushortT* __restrict__ nqB) {
    int b = blockIdx.x;
    int w = threadIdx.x >> 6, lane = threadIdx.x & 63;
    int q = blockIdx.y * 4 + w;  // grid.y = 225, 900 = 4*225
    int bin = binsO[b * Qn + q];
    float4 v = qf[(size_t)(b * Qn + q) * (Hn / 4) + lane];
    float4 wv = W[(size_t)bin * (Hn / 4) + lane];
    v.x += wv.x; v.y += wv.y; v.z += wv.z; v.w += wv.w;
    float ss = v.x * v.x + v.y * v.y + v.z * v.z + v.w * v.w;
    #pragma unroll
    for (int off = 32; off >= 1; off >>= 1) ss += __shfl_xor(ss, off, 64);
    float sc = 1.f / fmaxf(sqrtf(ss), 1e-12f);
    float xs[4] = {v.x * sc, v.y * sc, v.z * sc, v.w * sc};
    ushort4 p0, p1;
    ushortT* h0 = (ushortT*)&p0; ushortT* h1 = (ushortT*)&p1;
    #pragma unroll
    for (int c = 0; c < 4; c++) {
        float f0, f1;
        h0[c] = bf16rne(xs[c], f0);
        float r1 = xs[c] - f0;
        h1[c] = bf16rne(r1, f1);
    }
    int sp = sortPos[b * Qn + q];
    size_t base = ((size_t)(b * Qn + sp)) * Hn + lane * 4;
    *(ushort4*)(nqB + 0 * PS + base) = p0;
    *(ushort4*)(nqB + 1 * PS + base) = p1;
}

// ---------------- K2: MFMA pair-sim GEMM + segment argmax + top4 -------------
// R9 structure (session best): 64x64 tiles, 1920 blocks, LDS DMA staging with
// XOR swizzle, LDS-side emission (R2/R5/R7: anything else spills acc).
// R10 lesson: direct-global frag loads = 16 scattered 64B lines/instruction ->
// request-rate bound, 102us. LDS staging reverted.
// This round: bf16x2 -> 4 DMA + 8 ds_read + 16 MFMA per wave-chunk (each -33%).
__global__ __launch_bounds__(256, 4) void k2_gemm(
        const ushortT* __restrict__ nqB, const int* __restrict__ binSorted,
        const int* __restrict__ origIdx, u64* __restrict__ segBest,
        float* __restrict__ topCand) {
    // stage: 4 regions (A0,A1,B0,B1) x 64 rows x 32 elems (64B/row, swizzled)
    // = 16KB. After the K-loop, reused as segLds[NB2] (10.4KB).
    __shared__ __align__(16) union ShMem {
        ushortT stage[4 * 2048];   // 16 KB
        u64     segLds[NB2];       // 10.4 KB
    } sh;
    __shared__ int rbins[T64], cbins[T64], rois[T64], cois[T64];
    __shared__ float t4w[16];

    int lin = blockIdx.x;
    int xcd = lin & 7;
    int slot = lin >> 3;                 // 0..239
    int b = xcd * 2 + (slot >= NP64 ? 1 : 0);
    int tp = (slot >= NP64) ? slot - NP64 : slot;
    int ti = 0, rem = tp;
    while (rem >= NTILE64 - ti) { rem -= NTILE64 - ti; ti++; }
    int tj = ti + rem;
    int rowBase = ti * T64, colBase = tj * T64;
    int t = threadIdx.x;
    int w = t >> 6, lane = t & 63;
    int wrow = w >> 1, wcol = w & 1;
    int lq = lane >> 4, lm = lane & 15;

    if (t < T64) {
        int sr = rowBase + t, sc = colBase + t;
        rbins[t] = (sr < Qn) ? binSorted[b * Qn + sr] : 0;
        rois[t]  = (sr < Qn) ? origIdx[b * Qn + sr] : 0;
        cbins[t] = (sc < Qn) ? binSorted[b * Qn + sc] : 0;
        cois[t]  = (sc < Qn) ? origIdx[b * Qn + sc] : 0;
    }

    f32x4 acc[2][2];
    #pragma unroll
    for (int i = 0; i < 2; i++)
        #pragma unroll
        for (int j = 0; j < 2; j++) acc[i][j] = (f32x4){0.f, 0.f, 0.f, 0.f};

    // staging: per chunk 4 DMA issues (A-plane0, A-plane1, B-plane0, B-plane1),
    // each 4KB: thread t covers row = t>>2, LDS slot = t&3, fetching data unit
    // (t&3)^((t>>3)&3)  (XOR swizzle so frag reads are 2-way / free).
    u32 goff[4];
    int loff[4];
    #pragma unroll
    for (int i = 0; i < 4; i++) {
        int p = i & 1;                       // plane
        int sideB = i >> 1;                  // 0 = A rows, 1 = B rows
        int row = t >> 2;
        int udata = (t & 3) ^ ((t >> 3) & 3);
        int gq = (sideB ? colBase : rowBase) + row;
        if (gq >= Qn) gq = Qn - 1;
        goff[i] = (u32)(p * (u32)PS) + (u32)(b * Qn + gq) * Hn + (u32)(udata * 8);
        loff[i] = i * 2048 + t * 8;
    }
    int aswz = (lq ^ ((lm >> 1) & 3)) * 8;   // swizzled 16B-unit offset

    for (int kc = 0; kc < Hn; kc += 32) {
        #pragma unroll
        for (int i = 0; i < 4; i++)
            gl_lds16(nqB + goff[i] + kc, &sh.stage[loff[i]]);
        __syncthreads();   // vmcnt(0) drain before barrier

        short8 af[2][2];
        #pragma unroll
        for (int p = 0; p < 2; p++)
            #pragma unroll
            for (int mt = 0; mt < 2; mt++)
                af[p][mt] = *(const short8*)&sh.stage[p * 2048 + (wrow * 32 + mt * 16 + lm) * 32 + aswz];

        #pragma unroll
        for (int nt = 0; nt < 2; nt++) {
            int coff = (wcol * 32 + nt * 16 + lm) * 32 + aswz;
            short8 b0 = *(const short8*)&sh.stage[2 * 2048 + coff];
            short8 b1 = *(const short8*)&sh.stage[3 * 2048 + coff];
            #pragma unroll
            for (int mt = 0; mt < 2; mt++) {
                f32x4 c = acc[mt][nt];
                c = __builtin_amdgcn_mfma_f32_16x16x32_bf16(af[0][mt], b0, c, 0, 0, 0);
                c = __builtin_amdgcn_mfma_f32_16x16x32_bf16(af[0][mt], b1, c, 0, 0, 0);
                c = __builtin_amdgcn_mfma_f32_16x16x32_bf16(af[1][mt], b0, c, 0, 0, 0);
                c = __builtin_amdgcn_mfma_f32_16x16x32_bf16(af[1][mt], b1, c, 0, 0, 0);
                acc[mt][nt] = c;
            }
        }
        __syncthreads();   // frag reads done before next chunk's DMA writes
    }

    // ---- repurpose stage memory as segLds; zero it ----
    for (int s = t; s < NB2; s += 256) sh.segLds[s] = 0ULL;
    __syncthreads();

    // ---- emission: C/D layout col=lm, row=lq*4+reg (m89-verified) ----
    float t4[4] = {-3e38f, -3e38f, -3e38f, -3e38f};
    int curSeg = -1; u64 curBest = 0ULL;
    #pragma unroll
    for (int mt = 0; mt < 2; mt++) {
        #pragma unroll
        for (int r = 0; r < 4; r++) {
            int lrr = wrow * 32 + mt * 16 + lq * 4 + r;
            int sr = rowBase + lrr;
            int bi = rbins[lrr], io = rois[lrr];
            #pragma unroll
            for (int nt = 0; nt < 2; nt++) {
                int lcc = wcol * 32 + nt * 16 + lm;
                int sc = colBase + lcc;
                bool ok = (sr < Qn) && (sc < Qn) && (sr < sc);
                if (ok) {
                    float v = acc[mt][nt][r];
                    ins4(t4, v);
                    int bj = cbins[lcc], jo = cois[lcc];
                    int bmin = bi < bj ? bi : bj, bmax = bi < bj ? bj : bi;
                    int seg = bmin * NBINS + bmax;
                    int imin = io < jo ? io : jo, jmax = io < jo ? jo : io;
                    u64 packed = ((u64)fkey(v) << 32) | (u32)(~(((u32)imin << 10) | (u32)jmax));
                    if (seg == curSeg) { if (packed > curBest) curBest = packed; }
                    else {
                        if (curSeg >= 0) atomicMax(&sh.segLds[curSeg], curBest);
                        curSeg = seg; curBest = packed;
                    }
                }
            }
        }
    }
    if (curSeg >= 0) atomicMax(&sh.segLds[curSeg], curBest);

    // wave-level top4 shuffle merge
    #pragma unroll
    for (int off = 32; off >= 1; off >>= 1) {
        float o0 = __shfl_xor(t4[0], off, 64);
        float o1 = __shfl_xor(t4[1], off, 64);
        float o2 = __shfl_xor(t4[2], off, 64);
        float o3 = __shfl_xor(t4[3], off, 64);
        ins4(t4, o0); ins4(t4, o1); ins4(t4, o2); ins4(t4, o3);
    }
    if (lane == 0) {
        t4w[w * 4 + 0] = t4[0]; t4w[w * 4 + 1] = t4[1];
        t4w[w * 4 + 2] = t4[2]; t4w[w * 4 + 3] = t4[3];
    }
    __syncthreads();

    for (int s = t; s < NB2; s += 256) {
        u64 v = sh.segLds[s];
        if (v) atomicMax(&segBest[(size_t)b * NB2 + s], v);
    }
    if (t == 0) {
        #pragma unroll
        for (int ww = 1; ww < 4; ww++) {
            ins4(t4, t4w[ww * 4 + 0]); ins4(t4, t4w[ww * 4 + 1]);
            ins4(t4, t4w[ww * 4 + 2]); ins4(t4, t4w[ww * 4 + 3]);
        }
        float* dst = topCand + (size_t)(b * NP64 + tp) * 4;
        dst[0] = t4[0]; dst[1] = t4[1]; dst[2] = t4[2]; dst[3] = t4[3];
    }
}

// ---------------- K3 helpers (NT3 = 1024) ------------------------------------
__device__ __forceinline__ int blockSumI(int v, volatile int* red) {
    #pragma unroll
    for (int off = 32; off >= 1; off >>= 1) v += __shfl_xor(v, off, 64);
    int w = threadIdx.x >> 6;
    if ((threadIdx.x & 63) == 0) red[w] = v;
    __syncthreads();
    if (threadIdx.x < 64) {
        int x = (threadIdx.x < 16) ? red[threadIdx.x] : 0;
        #pragma unroll
        for (int off = 8; off >= 1; off >>= 1) x += __shfl_xor(x, off, 64);
        if (threadIdx.x == 0) red[0] = x;
    }
    __syncthreads();
    int r = red[0];
    __syncthreads();
    return r;
}
__device__ __forceinline__ float blockSumF(float v, volatile float* red) {
    #pragma unroll
    for (int off = 32; off >= 1; off >>= 1) v += __shfl_xor(v, off, 64);
    int w = threadIdx.x >> 6;
    if ((threadIdx.x & 63) == 0) red[w] = v;
    __syncthreads();
    if (threadIdx.x < 64) {
        float x = (threadIdx.x < 16) ? red[threadIdx.x] : 0.f;
        #pragma unroll
        for (int off = 8; off >= 1; off >>= 1) x += __shfl_xor(x, off, 64);
        if (threadIdx.x == 0) red[0] = x;
    }
    __syncthreads();
    float r = red[0];
    __syncthreads();
    return r;
}
__device__ __forceinline__ u32 blockMinU(u32 v, volatile u32* red) {
    #pragma unroll
    for (int off = 32; off >= 1; off >>= 1) {
        u32 o = (u32)__shfl_xor((int)v, off, 64);
        v = v < o ? v : o;
    }
    int w = threadIdx.x >> 6;
    if ((threadIdx.x & 63) == 0) red[w] = v;
    __syncthreads();
    if (threadIdx.x < 64) {
        u32 x = (threadIdx.x < 16) ? red[threadIdx.x] : 0xFFFFFFFFu;
        #pragma unroll
        for (int off = 8; off >= 1; off >>= 1) {
            u32 o = (u32)__shfl_xor((int)x, off, 64);
            x = x < o ? x : o;
        }
        if (threadIdx.x == 0) red[0] = x;
    }
    __syncthreads();
    u32 r = red[0];
    __syncthreads();
    return r;
}
// block top-2 (max, 2nd max incl. duplicates); inputs per-thread (m1,m2)
__device__ void blockTop2(float m1, float m2, volatile float* red2, float& o1, float& o2) {
    #pragma unroll
    for (int off = 32; off >= 1; off >>= 1) {
        float a1 = __shfl_xor(m1, off, 64);
        float a2 = __shfl_xor(m2, off, 64);
        ins2(m1, m2, a1); ins2(m1, m2, a2);
    }
    int w = threadIdx.x >> 6;
    if ((threadIdx.x & 63) == 0) { red2[w * 2] = m1; red2[w * 2 + 1] = m2; }
    __syncthreads();
    if (threadIdx.x == 0) {
        float r1 = red2[0], r2 = red2[1];
        for (int ww = 1; ww < 16; ww++) { ins2(r1, r2, red2[ww * 2]); ins2(r1, r2, red2[ww * 2 + 1]); }
        red2[0] = r1; red2[1] = r2;
    }
    __syncthreads();
    o1 = red2[0]; o2 = red2[1];
    __syncthreads();
}

// Count-based rank selection (used only for the tiny median set).
__device__ void selectTwoC(const u32* ckeys, int m, int mp, int p0, int p1,
                           u32& r0, u32& r1, volatile u32* redU) {
    int t = threadIdx.x;
    u32 kA = (t < m) ? ckeys[t] : 0xFFFFFFFFu;
    u32 kB = (t + NT3 < m) ? ckeys[t + NT3] : 0xFFFFFFFFu;
    int cA = 0, cB = 0;
    if (t < m) {
        const uint4* c4 = (const uint4*)ckeys;
        for (int g = 0; g < mp / 16; g++) {
            uint4 a = c4[g * 4 + 0], bq = c4[g * 4 + 1];
            uint4 c = c4[g * 4 + 2], d = c4[g * 4 + 3];
            u32 ys[16] = {a.x, a.y, a.z, a.w, bq.x, bq.y, bq.z, bq.w,
                          c.x, c.y, c.z, c.w, d.x, d.y, d.z, d.w};
            #pragma unroll
            for (int j = 0; j < 16; j++) {
                cA += (ys[j] <= kA);
                cB += (ys[j] <= kB);
            }
        }
    }
    u32 q0 = 0xFFFFFFFFu, q1 = 0xFFFFFFFFu;
    if (cA >= p0 + 1 && kA < q0) q0 = kA;
    if (cB >= p0 + 1 && kB < q0) q0 = kB;
    if (cA >= p1 + 1 && kA < q1) q1 = kA;
    if (cB >= p1 + 1 && kB < q1) q1 = kB;
    r0 = blockMinU(q0, redU);
    r1 = blockMinU(q1, redU);
}

// masked quantile at q=1-1/(n+1): pos = n-2 + 2/(n+1) -> lo=n-2, hi=n-1,
// i.e. interpolation between 2nd-max and max (same float arithmetic as ref).
__device__ __forceinline__ float quantTop2(float top1, float top2, int n) {
    float nf = (float)n;
    float qq = 1.f - 1.f / (nf + 1.f);
    float pos = qq * fmaxf(nf - 1.f, 0.f);
    int lo = (int)floorf(pos), hi = (int)ceilf(pos);
    float frac = pos - (float)lo;
    float slo = (lo >= n - 1) ? top1 : top2;
    float shi = (hi >= n - 1) ? top1 : top2;
    return slo + (shi - slo) * frac;
}

// ---------------- K3: per-batch scalar tail + fused final combine ------------
__global__ __launch_bounds__(1024) void k3_final(
        const u64* __restrict__ segBest, const float* __restrict__ anglesO,
        const float* __restrict__ topCand, float* __restrict__ batchRes,
        u32* __restrict__ counter, float* __restrict__ out) {
    int b = blockIdx.x, t = threadIdx.x;
    int lane = t & 63;
    __shared__ float sval[NB2], sd[NB2], sai[NB2], saj[NB2];
    __shared__ unsigned char svalid[NB2], smF[NB2];
    __shared__ __align__(16) u32 ckeys[NB2 + 16];
    __shared__ int redI[32];
    __shared__ float redF[32];
    __shared__ u32 redU[32];
    __shared__ float red2[32];
    __shared__ int mcnt;
    __shared__ float sth2;

    for (int s = t; s < NB2; s += NT3) {
        u64 p = segBest[(size_t)b * NB2 + s];
        bool v = (p != 0ULL);
        float val = 0.f, ai = 0.f, aj = 0.f, d = 0.f;
        if (v) {
            val = unfkey((u32)(p >> 32));
            u32 code = ~((u32)p);
            int i = (code >> 10) & 1023, j = code & 1023;
            ai = anglesO[b * Qn + i]; aj = anglesO[b * Qn + j];
            d = circdist(ai, aj);
        }
        sval[s] = val; sai[s] = ai; saj[s] = aj; sd[s] = d;
        svalid[s] = v ? 1 : 0;
    }
    __syncthreads();

    // ---- S + top2 of valid sims -> thr ----
    int Sv = 0;
    float m1 = -3e38f, m2 = -3e38f;
    for (int s = t; s < NB2; s += NT3) {
        if (svalid[s]) { Sv++; ins2(m1, m2, sval[s]); }
    }
    int S = blockSumI(Sv, redI);
    float top1, top2v;
    blockTop2(m1, m2, red2, top1, top2v);
    float thr = (S == 0) ? BIGV : quantTop2(top1, top2v, S);

    int c1v = 0;
    for (int s = t; s < NB2; s += NT3) if (svalid[s] && sval[s] > thr) c1v++;
    int c1 = blockSumI(c1v, redI);

    // ---- th2 = 4th-largest pair sim (wave-0 top4 shuffle merge) ----
    if (t < 64) {
        float t4[4] = {-3e38f, -3e38f, -3e38f, -3e38f};
        for (int i = t; i < NP64 * 4; i += 64) ins4(t4, topCand[(size_t)b * NP64 * 4 + i]);
        #pragma unroll
        for (int off = 32; off >= 1; off >>= 1) {
            float o0 = __shfl_xor(t4[0], off, 64);
            float o1 = __shfl_xor(t4[1], off, 64);
            float o2 = __shfl_xor(t4[2], off, 64);
            float o3 = __shfl_xor(t4[3], off, 64);
            ins4(t4, o0); ins4(t4, o1); ins4(t4, o2); ins4(t4, o3);
        }
        if (t == 0) sth2 = t4[3];
    }
    __syncthreads();
    float th2 = sth2;

    bool use_fb = (c1 < 2);
    int cv = 0;
    for (int s = t; s < NB2; s += NT3) {
        bool mF = use_fb ? (svalid[s] && sval[s] >= th2) : (svalid[s] && sval[s] > thr);
        smF[s] = mF ? 1 : 0;
        cv += mF ? 1 : 0;
    }
    int cnt = blockSumI(cv, redI);

    // ---- median of masked d: compact (tiny set) + rank select ----
    if (t == 0) mcnt = 0;
    __syncthreads();
    for (int s = t; s < NB2; s += NT3) {
        bool pred = smF[s] != 0;
        u32 key = fkey(sd[s]);
        u64 bal = __ballot(pred);
        int prefix = __popcll(bal & ((1ULL << lane) - 1ULL));
        int tot = __popcll(bal);
        int base = 0;
        if (lane == 0) base = tot ? atomicAdd(&mcnt, tot) : 0;
        base = __shfl(base, 0, 64);
        if (pred) ckeys[base + prefix] = key;
    }
    __syncthreads();
    int m2c = mcnt;
    int mp2 = (m2c + 15) & ~15;
    for (int s = m2c + t; s < mp2; s += NT3) ckeys[s] = 0xFFFFFFFFu;
    __syncthreads();

    float med;
    if (cnt == 0) med = BIGV;
    else {
        int midx = (cnt - 1) >> 1;
        u32 kk0, kk1;
        selectTwoC(ckeys, m2c, mp2, midx, midx, kk0, kk1, redU);
        med = unfkey(kk0);
    }
    float alpha = fminf(fmaxf(med, PI_F / (float)NBINS), HALF_PI_F);

    // ---- coop stats + comp count/top2 in one pass ----
    int ncoopv = 0, ncompv = 0; float coopv = 0.f;
    float c1m = -3e38f, c2m = -3e38f;
    for (int s = t; s < NB2; s += NT3) {
        if (!smF[s]) continue;
        if (sd[s] <= alpha) {
            ncoopv++;
            float ai = sai[s], aj = saj[s];
            float mm = atan2f((sinf(ai) + sinf(aj)) * 0.5f, (cosf(ai) + cosf(aj)) * 0.5f);
            float d1 = circdist(ai, mm), d2 = circdist(aj, mm);
            coopv += d1 * d1 + d2 * d2;
        } else {
            ncompv++;
            ins2(c1m, c2m, sval[s]);
        }
    }
    int ncoop = blockSumI(ncoopv, redI);
    float coopSum = blockSumF(coopv, redF);
    int ncomp = blockSumI(ncompv, redI);
    float ct1, ct2;
    blockTop2(c1m, c2m, red2, ct1, ct2);
    float margin = (ncomp == 0) ? BIGV : quantTop2(ct1, ct2, ncomp);

    float compv = 0.f;
    for (int s = t; s < NB2; s += NT3) {
        if (smF[s] && sd[s] > alpha) {
            float viol = fmaxf(sval[s] - margin, 0.f);
            compv += viol * viol;
        }
    }
    float compSum = blockSumF(compv, redF);

    // fused final combine: last-finished block reduces all batchRes.
    if (t == 0) {
        float r0 = coopSum / (float)(ncoop > 1 ? ncoop : 1);
        float r1 = compSum / (float)(ncomp > 1 ? ncomp : 1);
        float r2 = cnt > 0 ? 1.f : 0.f;
        __hip_atomic_store(&batchRes[b * 3 + 0], r0, __ATOMIC_RELEASE, __HIP_MEMORY_SCOPE_AGENT);
        __hip_atomic_store(&batchRes[b * 3 + 1], r1, __ATOMIC_RELEASE, __HIP_MEMORY_SCOPE_AGENT);
        __hip_atomic_store(&batchRes[b * 3 + 2], r2, __ATOMIC_RELEASE, __HIP_MEMORY_SCOPE_AGENT);
        u32 done = __hip_atomic_fetch_add(counter, 1u, __ATOMIC_ACQ_REL, __HIP_MEMORY_SCOPE_AGENT);
        if (done == Bn - 1) {
            float cs = 0.f, ps = 0.f, vs = 0.f;
            for (int bb = 0; bb < Bn; bb++) {
                cs += __hip_atomic_load(&batchRes[bb * 3 + 0], __ATOMIC_ACQUIRE, __HIP_MEMORY_SCOPE_AGENT);
                ps += __hip_atomic_load(&batchRes[bb * 3 + 1], __ATOMIC_ACQUIRE, __HIP_MEMORY_SCOPE_AGENT);
                vs += __hip_atomic_load(&batchRes[bb * 3 + 2], __ATOMIC_ACQUIRE, __HIP_MEMORY_SCOPE_AGENT);
            }
            float denom = fmaxf(vs, 1.f);
            out[0] = cs / denom;
            out[1] = ps / denom;
        }
    }
}

extern "C" void kernel_launch(void* const* d_in, const int* in_sizes, int n_in,
                              void* d_out, int out_size, void* d_ws, size_t ws_size,
                              hipStream_t stream) {
    (void)in_sizes; (void)n_in; (void)out_size; (void)ws_size;
    const float* qf = (const float*)d_in[0];
    const float* pa = (const float*)d_in[1];
    const float* W  = (const float*)d_in[2];
    float* out = (float*)d_out;

    char* ws = (char*)d_ws;
    size_t off = 0;
    ushortT* nqB = (ushortT*)(ws + off);  off += 2 * PS * 2;                 // 14.7 MB
    float* anglesO = (float*)(ws + off);  off += (size_t)Bn * Qn * 4;
    int* binsO = (int*)(ws + off);        off += (size_t)Bn * Qn * 4;
    int* sortPos = (int*)(ws + off);      off += (size_t)Bn * Qn * 4;
    int* origIdx = (int*)(ws + off);      off += (size_t)Bn * Qn * 4;
    int* binSorted = (int*)(ws + off);    off += (size_t)Bn * Qn * 4;
    u64* segBest = (u64*)(ws + off);      off += (size_t)Bn * NB2 * 8;
    float* topCand = (float*)(ws + off);  off += (size_t)Bn * NP64 * 4 * 4;
    float* batchRes = (float*)(ws + off); off += (size_t)Bn * 3 * 4;
    u32* counter = (u32*)(ws + off);      off += 64;

    k0_sort<<<Bn, 256, 0, stream>>>(pa, anglesO, binsO, sortPos, origIdx, binSorted,
                                    segBest, counter);
    k1_norm<<<dim3(Bn, 225), 256, 0, stream>>>((const float4*)qf, (const float4*)W,
                                               binsO, sortPos, nqB);
    k2_gemm<<<NP64 * Bn, 256, 0, stream>>>(nqB, binSorted, origIdx, segBest, topCand);
    k3_final<<<Bn, 1024, 0, stream>>>(segBest, anglesO, topCand, batchRes, counter, out);
}